// Round 2
// 1384.450 us; speedup vs baseline: 1.0624x; 1.0624x over previous
//
#include <hip/hip_runtime.h>
#include <stdint.h>

// ---------- types / helpers ----------
typedef __bf16 bf16x8 __attribute__((ext_vector_type(8)));
typedef float  f32x4  __attribute__((ext_vector_type(4)));

__device__ __forceinline__ uint16_t f2b(float f) {
  uint32_t u = __float_as_uint(f);
  u += 0x7fffu + ((u >> 16) & 1u);        // round-to-nearest-even
  return (uint16_t)(u >> 16);
}
__device__ __forceinline__ float b2f(uint16_t h) {
  return __uint_as_float(((uint32_t)h) << 16);
}

// async global->LDS, 16B per lane; LDS dst = wave-uniform base + lane*16
__device__ __forceinline__ void gl_lds16(const uint16_t* g, uint16_t* l) {
  __builtin_amdgcn_global_load_lds(
      (const __attribute__((address_space(1))) uint32_t*)g,
      (__attribute__((address_space(3))) uint32_t*)l, 16, 0, 0);
}

#define MFMA16(a,b,c) __builtin_amdgcn_mfma_f32_16x16x32_bf16((a),(b),(c),0,0,0)

// B=2 S=2048 DIM=2048 HEADS=16 HD=128 FF=8192 PREV=1024 T=3072

// ---------- rmsnorm (f32 in -> bf16 out), row length 2048 ----------
__global__ __launch_bounds__(256)
void rmsnorm_k(const float* __restrict__ x, const float* __restrict__ w,
               uint16_t* __restrict__ out) {
  __shared__ float red[4];
  const int row = blockIdx.x, tid = threadIdx.x;
  const float* xr = x + (size_t)row * 2048;
  const int c = tid * 8;
  float4 a = *(const float4*)&xr[c];
  float4 b = *(const float4*)&xr[c + 4];
  float ss = a.x*a.x + a.y*a.y + a.z*a.z + a.w*a.w
           + b.x*b.x + b.y*b.y + b.z*b.z + b.w*b.w;
  ss += __shfl_xor(ss, 1);  ss += __shfl_xor(ss, 2);  ss += __shfl_xor(ss, 4);
  ss += __shfl_xor(ss, 8);  ss += __shfl_xor(ss, 16); ss += __shfl_xor(ss, 32);
  if ((tid & 63) == 0) red[tid >> 6] = ss;
  __syncthreads();
  const float tot = red[0] + red[1] + red[2] + red[3];
  const float rms = rsqrtf(tot * (1.0f / 2048.0f) + 1e-6f);
  float4 w0 = *(const float4*)&w[c];
  float4 w1 = *(const float4*)&w[c + 4];
  uint16_t* orow = out + (size_t)row * 2048;
  orow[c+0] = f2b(a.x * rms * w0.x); orow[c+1] = f2b(a.y * rms * w0.y);
  orow[c+2] = f2b(a.z * rms * w0.z); orow[c+3] = f2b(a.w * rms * w0.w);
  orow[c+4] = f2b(b.x * rms * w1.x); orow[c+5] = f2b(b.y * rms * w1.y);
  orow[c+6] = f2b(b.z * rms * w1.z); orow[c+7] = f2b(b.w * rms * w1.w);
}

// ---------- bias concat: [bq|bk|bv] -> 6144 f32 ----------
__global__ void biascat_k(const float* __restrict__ bq, const float* __restrict__ bk,
                          const float* __restrict__ bv, float* __restrict__ out) {
  int i = blockIdx.x * 256 + threadIdx.x;
  if (i < 6144)
    out[i] = (i < 2048) ? bq[i] : ((i < 4096) ? bk[i - 2048] : bv[i - 4096]);
}

// ---------- transpose-convert: src (K,N) f32 -> dst (N,K) bf16 ----------
__global__ __launch_bounds__(256)
void transpose_k(const float* __restrict__ src, uint16_t* __restrict__ dst,
                 int K, int N) {
  __shared__ float tile[32][33];
  const int tx = threadIdx.x & 31, ty = threadIdx.x >> 5;   // 32 x 8
  const int n0 = blockIdx.x * 32, k0 = blockIdx.y * 32;
  #pragma unroll
  for (int i = 0; i < 4; ++i)
    tile[ty + i*8][tx] = src[(size_t)(k0 + ty + i*8) * N + n0 + tx];
  __syncthreads();
  #pragma unroll
  for (int i = 0; i < 4; ++i)
    dst[(size_t)(n0 + ty + i*8) * K + k0 + tx] = f2b(tile[tx][ty + i*8]);
}

// ---------- batched V transpose: (32,3072,128) f32 -> (32,128,3072) bf16 ----------
__global__ __launch_bounds__(256)
void transpose_v_k(const float* __restrict__ src, uint16_t* __restrict__ dst) {
  __shared__ float tile[32][33];
  const int tx = threadIdx.x & 31, ty = threadIdx.x >> 5;
  const int t0 = blockIdx.x * 32, d0 = blockIdx.y * 32, bh = blockIdx.z;
  const float* s = src + (size_t)bh * 393216;
  uint16_t*   d = dst + (size_t)bh * 393216;
  #pragma unroll
  for (int i = 0; i < 4; ++i)
    tile[ty + i*8][tx] = s[(size_t)(t0 + ty + i*8) * 128 + d0 + tx];
  __syncthreads();
  #pragma unroll
  for (int i = 0; i < 4; ++i)
    d[(size_t)(d0 + ty + i*8) * 3072 + t0 + tx] = f2b(tile[tx][ty + i*8]);
}

// ---------- KV-cache copy: (BH,1024,128) f32 -> (BH,3072,128) f32 [:1024] ----------
__global__ __launch_bounds__(256)
void copy_cache_k(const float4* __restrict__ src, float4* __restrict__ dst) {
  const int idx = blockIdx.x * 256 + threadIdx.x;      // 1,048,576 total
  const int c4 = idx & 31, t = (idx >> 5) & 1023, bh = idx >> 15;
  dst[((size_t)bh * 3072 + t) * 32 + c4] = src[idx];
}

// ---------- KV-cache copy + fused bf16 convert (K path) ----------
__global__ __launch_bounds__(256)
void copy_cache_kb_k(const float4* __restrict__ src, float4* __restrict__ dst,
                     uint16_t* __restrict__ dstb) {
  const int idx = blockIdx.x * 256 + threadIdx.x;      // 1,048,576 total
  const int c4 = idx & 31, t = (idx >> 5) & 1023, bh = idx >> 15;
  float4 v = src[idx];
  const size_t o = ((size_t)bh * 3072 + t) * 32 + c4;
  dst[o] = v;
  ushort4 b;
  b.x = f2b(v.x); b.y = f2b(v.y); b.z = f2b(v.z); b.w = f2b(v.w);
  ((ushort4*)dstb)[o] = b;
}

// ---------- RoPE + scatter (K also emitted as bf16 -> kbb) ----------
__global__ __launch_bounds__(256)
void rope_k(const uint16_t* __restrict__ qkv, const float* __restrict__ fc,
            const float* __restrict__ fs, uint16_t* __restrict__ qb,
            float* __restrict__ kat, float* __restrict__ vat,
            uint16_t* __restrict__ kbb) {
  const int bi = blockIdx.x;                // B*S*4 = 16384 blocks
  const int bs = bi >> 2;                   // b*2048 + s
  const int h  = ((bi & 3) << 2) + (threadIdx.x >> 6);
  const int d  = threadIdx.x & 63;
  const int b  = bs >> 11, s = bs & 2047;
  const int pos = s + 1024;
  const float c  = fc[pos * 64 + d];
  const float sn = fs[pos * 64 + d];
  const uint16_t* row = qkv + (size_t)bs * 6144 + h * 128;
  const float q0 = b2f(row[2*d]),        q1 = b2f(row[2*d + 1]);
  const float k0 = b2f(row[2048 + 2*d]), k1 = b2f(row[2048 + 2*d + 1]);
  const float v0 = b2f(row[4096 + 2*d]), v1 = b2f(row[4096 + 2*d + 1]);
  const size_t qo = (((size_t)b*16 + h) * 2048 + s) * 128 + 2*d;
  qb[qo]     = f2b(q0 * c - q1 * sn);
  qb[qo + 1] = f2b(q0 * sn + q1 * c);
  const size_t ko = (((size_t)b*16 + h) * 3072 + 1024 + s) * 128 + 2*d;
  const float kr0 = k0 * c - k1 * sn;
  const float kr1 = k0 * sn + k1 * c;
  kat[ko]     = kr0;
  kat[ko + 1] = kr1;
  kbb[ko]     = f2b(kr0);
  kbb[ko + 1] = f2b(kr1);
  vat[ko]     = v0;
  vat[ko + 1] = v1;
}

// ---------- flash attention v3: KVBLK=64, swizzled K+V, deferred l-reduce ----------
__global__ __launch_bounds__(256)
void attn_k(const uint16_t* __restrict__ qb, const uint16_t* __restrict__ kb,
            const uint16_t* __restrict__ vt, uint16_t* __restrict__ ob) {
  __shared__ __align__(16) uint16_t lsK[64 * 128];  // [key][chunk^(key&15)] swizzled
  __shared__ __align__(16) uint16_t lsV[128 * 64];  // [d][chunk^(d&7)] swizzled, ld=64
  __shared__ __align__(16) uint16_t lsP[4][16 * 72];
  const int tid = threadIdx.x;
  const int lane = tid & 63, w = tid >> 6;
  const int l15 = lane & 15, q4 = lane >> 4;
  const int bh = blockIdx.x & 31;                   // b*16+h
  const int qi = 31 - (blockIdx.x >> 5);            // largest-work blocks first
  const int q0 = qi * 64;
  const int s_w = q0 + w * 16;

  // staging source offsets (element units); LDS dest is linear (gl_lds requirement),
  // source is pre-swizzled so the read-side XOR retrieves natural chunks.
  int koff[4], voff[4];
  #pragma unroll
  for (int p = 0; p < 4; ++p) {
    const int idk = p * 256 + tid;                  // 1024 chunks of 8 elements
    const int krow = idk >> 4, kch = idk & 15;
    koff[p] = krow * 128 + ((kch ^ (krow & 15)) << 3);
    const int dd = idk >> 3, vch = idk & 7;
    voff[p] = dd * 3072 + ((vch ^ (dd & 7)) << 3);
  }
  const uint16_t* kbh = kb + (size_t)bh * 3072 * 128;
  const uint16_t* vbh = vt + (size_t)bh * 128 * 3072;

  // Q fragments (A-operand): m=l15, k=kc*32+q4*8+j
  bf16x8 qf[4];
  const uint16_t* qrow = qb + ((size_t)bh * 2048 + s_w + l15) * 128;
  #pragma unroll
  for (int kc = 0; kc < 4; ++kc)
    qf[kc] = *(const bf16x8*)&qrow[kc * 32 + q4 * 8];

  f32x4 o[8];
  #pragma unroll
  for (int nt = 0; nt < 8; ++nt) o[nt] = (f32x4){0.f, 0.f, 0.f, 0.f};
  float mrow[4], lrow[4];
  #pragma unroll
  for (int r = 0; r < 4; ++r) { mrow[r] = -1e38f; lrow[r] = 0.f; }

  const float SC = 0.08838834764831845f * 1.4426950408889634f;
  const int ntiles = qi + 17;                       // 64-key tiles, covers 1024+q0+63
  const int limw = 1024 + s_w + 15;                 // wave's largest allowed key

  for (int tt = 0; tt < ntiles; ++tt) {
    const int t0 = tt << 6;
    __syncthreads();
    #pragma unroll
    for (int p = 0; p < 4; ++p) {
      gl_lds16(kbh + (size_t)t0 * 128 + koff[p], &lsK[(p * 256 + w * 64) * 8]);
      gl_lds16(vbh + t0 + voff[p],               &lsV[(p * 256 + w * 64) * 8]);
    }
    __syncthreads();
    if (t0 > limw) continue;                        // fully masked for this wave

    f32x4 s[4];
    #pragma unroll
    for (int kg = 0; kg < 4; ++kg) s[kg] = (f32x4){0.f,0.f,0.f,0.f};
    #pragma unroll
    for (int kc = 0; kc < 4; ++kc) {
      const int chp = ((kc * 4 + q4) ^ l15) << 3;
      bf16x8 kf0 = *(const bf16x8*)&lsK[ l15       * 128 + chp];
      bf16x8 kf1 = *(const bf16x8*)&lsK[(16 + l15) * 128 + chp];
      bf16x8 kf2 = *(const bf16x8*)&lsK[(32 + l15) * 128 + chp];
      bf16x8 kf3 = *(const bf16x8*)&lsK[(48 + l15) * 128 + chp];
      s[0] = MFMA16(qf[kc], kf0, s[0]);
      s[1] = MFMA16(qf[kc], kf1, s[1]);
      s[2] = MFMA16(qf[kc], kf2, s[2]);
      s[3] = MFMA16(qf[kc], kf3, s[3]);
    }
    if (t0 + 63 > 1024 + s_w) {                     // diagonal tile: mask (wave-uniform branch)
      #pragma unroll
      for (int r = 0; r < 4; ++r) {
        const int lim = 1024 + s_w + q4 * 4 + r;
        if (t0 +      l15 > lim) s[0][r] = -1e38f;
        if (t0 + 16 + l15 > lim) s[1][r] = -1e38f;
        if (t0 + 32 + l15 > lim) s[2][r] = -1e38f;
        if (t0 + 48 + l15 > lim) s[3][r] = -1e38f;
      }
    }
    float alpha[4];
    #pragma unroll
    for (int r = 0; r < 4; ++r) {
      float v = fmaxf(fmaxf(s[0][r], s[1][r]), fmaxf(s[2][r], s[3][r]));
      v = fmaxf(v, __shfl_xor(v, 1)); v = fmaxf(v, __shfl_xor(v, 2));
      v = fmaxf(v, __shfl_xor(v, 4)); v = fmaxf(v, __shfl_xor(v, 8));
      const float mn = fmaxf(mrow[r], v);
      alpha[r] = exp2f((mrow[r] - mn) * SC);
      mrow[r] = mn;
    }
    #pragma unroll
    for (int r = 0; r < 4; ++r) {
      const float nm = -mrow[r] * SC;
      const float p0 = exp2f(fmaf(s[0][r], SC, nm));
      const float p1 = exp2f(fmaf(s[1][r], SC, nm));
      const float p2 = exp2f(fmaf(s[2][r], SC, nm));
      const float p3 = exp2f(fmaf(s[3][r], SC, nm));
      // per-lane partial row sum; cross-lane reduce deferred to epilogue
      lrow[r] = fmaf(lrow[r], alpha[r], (p0 + p1) + (p2 + p3));
      const int pr = (q4 * 4 + r) * 72;
      lsP[w][pr +      l15] = f2b(p0);
      lsP[w][pr + 16 + l15] = f2b(p1);
      lsP[w][pr + 32 + l15] = f2b(p2);
      lsP[w][pr + 48 + l15] = f2b(p3);
    }
    const float as = alpha[0] * alpha[1] * alpha[2] * alpha[3];
    if (__any(as != 1.0f)) {                        // running max moved: rescale O
      #pragma unroll
      for (int nt = 0; nt < 8; ++nt)
        #pragma unroll
        for (int r = 0; r < 4; ++r) o[nt][r] *= alpha[r];
    }
    bf16x8 pf0 = *(const bf16x8*)&lsP[w][l15 * 72      + q4 * 8];
    bf16x8 pf1 = *(const bf16x8*)&lsP[w][l15 * 72 + 32 + q4 * 8];
    #pragma unroll
    for (int nt = 0; nt < 8; ++nt) {
      const int d = nt * 16 + l15;
      bf16x8 vf0 = *(const bf16x8*)&lsV[d * 64 + (( q4      ^ (d & 7)) << 3)];
      bf16x8 vf1 = *(const bf16x8*)&lsV[d * 64 + (((4 + q4) ^ (d & 7)) << 3)];
      o[nt] = MFMA16(pf0, vf0, o[nt]);
      o[nt] = MFMA16(pf1, vf1, o[nt]);
    }
  }
  const int b = bh >> 4, h = bh & 15;
  #pragma unroll
  for (int r = 0; r < 4; ++r) {
    float l = lrow[r];
    l += __shfl_xor(l, 1); l += __shfl_xor(l, 2);
    l += __shfl_xor(l, 4); l += __shfl_xor(l, 8);
    const float inv = 1.0f / l;
    const int s = s_w + q4 * 4 + r;
    uint16_t* orow = ob + ((size_t)b * 2048 + s) * 2048 + h * 128;
    #pragma unroll
    for (int nt = 0; nt < 8; ++nt)
      orow[nt * 16 + l15] = f2b(o[nt][r] * inv);
  }
}

// ---------- GEMM m97-style: async staging, 128x128 tile, BK=32 ----------
template <int EPI>
__global__ __launch_bounds__(256)
void gemm_k(const uint16_t* __restrict__ A, const uint16_t* __restrict__ Bt,
            const float* __restrict__ bias, const float* __restrict__ resid,
            const uint16_t* __restrict__ gbuf, void* __restrict__ outp,
            int M, int N, int K) {
  __shared__ __align__(16) uint16_t lsA[128 * 32];
  __shared__ __align__(16) uint16_t lsB[128 * 32];
  const int tid = threadIdx.x;
  const int lane = tid & 63, wvi = tid >> 6;
  const int l15 = lane & 15, q4 = lane >> 4;
  const int wm = wvi & 1, wn = wvi >> 1;
  const int m0 = blockIdx.y * 128, n0 = blockIdx.x * 128;
  const int lr = lane >> 2, lc = (lane & 3) << 3;

  f32x4 acc[4][4];
  #pragma unroll
  for (int i = 0; i < 4; ++i)
    #pragma unroll
    for (int j = 0; j < 4; ++j) acc[i][j] = (f32x4){0.f, 0.f, 0.f, 0.f};

  const uint16_t* Ab = A + (size_t)m0 * K;
  const uint16_t* Bb = Bt + (size_t)n0 * K;
  for (int k0 = 0; k0 < K; k0 += 32) {
    __syncthreads();
    #pragma unroll
    for (int p = 0; p < 2; ++p) {
      const int row = p * 64 + wvi * 16 + lr;
      gl_lds16(Ab + (size_t)row * K + k0 + lc, &lsA[(p * 256 + wvi * 64) * 8]);
      gl_lds16(Bb + (size_t)row * K + k0 + lc, &lsB[(p * 256 + wvi * 64) * 8]);
    }
    __syncthreads();
    bf16x8 af[4], bfr[4];
    #pragma unroll
    for (int i = 0; i < 4; ++i)
      af[i] = *(const bf16x8*)&lsA[(wm * 64 + i * 16 + l15) * 32 + q4 * 8];
    #pragma unroll
    for (int j = 0; j < 4; ++j)
      bfr[j] = *(const bf16x8*)&lsB[(wn * 64 + j * 16 + l15) * 32 + q4 * 8];
    #pragma unroll
    for (int i = 0; i < 4; ++i)
      #pragma unroll
      for (int j = 0; j < 4; ++j)
        acc[i][j] = MFMA16(af[i], bfr[j], acc[i][j]);
  }
  #pragma unroll
  for (int i = 0; i < 4; ++i) {
    #pragma unroll
    for (int j = 0; j < 4; ++j) {
      const int n = n0 + wn * 64 + j * 16 + l15;
      const float bn = bias[n];
      #pragma unroll
      for (int r = 0; r < 4; ++r) {
        const int m = m0 + wm * 64 + i * 16 + q4 * 4 + r;
        const size_t off = (size_t)m * N + n;
        const float v = acc[i][j][r] + bn;
        if (EPI == 0) {
          ((uint16_t*)outp)[off] = f2b(v);
        } else if (EPI == 1) {
          ((float*)outp)[off] = v + resid[off];
        } else {
          const float g = b2f(gbuf[off]);
          const float sg = g / (1.0f + __expf(-g));
          ((uint16_t*)outp)[off] = f2b(sg * v);
        }
      }
    }
  }
}

// ---------- launch ----------
extern "C" void kernel_launch(void* const* d_in, const int* in_sizes, int n_in,
                              void* d_out, int out_size, void* d_ws, size_t ws_size,
                              hipStream_t stream) {
  const float* x   = (const float*)d_in[0];
  const float* kc  = (const float*)d_in[1];
  const float* vc  = (const float*)d_in[2];
  const float* anw = (const float*)d_in[3];
  const float* fnw = (const float*)d_in[4];
  const float* wq  = (const float*)d_in[5];
  const float* bq  = (const float*)d_in[6];
  const float* wk  = (const float*)d_in[7];
  const float* bk  = (const float*)d_in[8];
  const float* wv_ = (const float*)d_in[9];
  const float* bv  = (const float*)d_in[10];
  const float* wo  = (const float*)d_in[11];
  const float* bo  = (const float*)d_in[12];
  const float* wg  = (const float*)d_in[13];
  const float* bg  = (const float*)d_in[14];
  const float* wva = (const float*)d_in[15];
  const float* bva = (const float*)d_in[16];
  const float* wp  = (const float*)d_in[17];
  const float* bp  = (const float*)d_in[18];
  const float* fc  = (const float*)d_in[19];
  const float* fs  = (const float*)d_in[20];

  float* out_x = (float*)d_out;               // (2,2048,2048)
  float* kat = out_x + 8388608;               // (2,16,3072,128)
  float* vat = kat + 12582912;

  char* ws = (char*)d_ws;
  // Lifetimes: h_b[0,16M) + wbuf[16M,48M) are dead between the QKV GEMM and the
  // wo-transpose; k_b/v_t live exactly in that window (copy_cache..attn_k).
  uint16_t* h_b   = (uint16_t*)(ws);                       // [0,16M)   h bf16
  uint16_t* wbuf  = (uint16_t*)(ws + 16777216);            // [16M,48M) transposed weights
  uint16_t* k_b   = (uint16_t*)(ws);                       // [0,24M)   K bf16 natural (attn window)
  uint16_t* v_t   = (uint16_t*)(ws + 25165824);            // [24M,48M) V bf16 transposed (attn window)
  uint16_t* qkv_b = (uint16_t*)(ws + 50331648);            // [48M,96M) qkv bf16
  uint16_t* q_b   = (uint16_t*)(ws + 100663296);           // [96M,112M) roped Q
  uint16_t* o_b   = (uint16_t*)(ws + 117440512);           // [112M,128M) attn out
  float*    x1    = (float*)   (ws + 134217728);           // [128M,160M) post-attn residual
  float*    bcat  = (float*)   (ws + 167772160);           // 24 KB
  uint16_t* g_b   = qkv_b;                                 // FFN overlay [48M,112M)

  // attention block
  rmsnorm_k<<<4096, 256, 0, stream>>>(x, anw, h_b);
  biascat_k<<<24, 256, 0, stream>>>(bq, bk, bv, bcat);
  transpose_k<<<dim3(64, 64), 256, 0, stream>>>(wq,  wbuf,               2048, 2048);
  transpose_k<<<dim3(64, 64), 256, 0, stream>>>(wk,  wbuf + 1*2048*2048, 2048, 2048);
  transpose_k<<<dim3(64, 64), 256, 0, stream>>>(wv_, wbuf + 2*2048*2048, 2048, 2048);
  gemm_k<0><<<dim3(48, 32), 256, 0, stream>>>(h_b, wbuf, bcat, nullptr, nullptr,
                                              (void*)qkv_b, 4096, 6144, 2048);
  copy_cache_kb_k<<<4096, 256, 0, stream>>>((const float4*)kc, (float4*)kat, k_b);
  copy_cache_k<<<4096, 256, 0, stream>>>((const float4*)vc, (float4*)vat);
  rope_k<<<16384, 256, 0, stream>>>(qkv_b, fc, fs, q_b, kat, vat, k_b);
  transpose_v_k<<<dim3(96, 4, 32), 256, 0, stream>>>(vat, v_t);   // V -> bf16 [d][t]
  attn_k<<<1024, 256, 0, stream>>>(q_b, k_b, v_t, o_b);
  transpose_k<<<dim3(64, 64), 256, 0, stream>>>(wo, wbuf, 2048, 2048);
  gemm_k<1><<<dim3(16, 32), 256, 0, stream>>>(o_b, wbuf, bo, x, nullptr,
                                              (void*)x1, 4096, 2048, 2048);
  // FFN block
  rmsnorm_k<<<4096, 256, 0, stream>>>(x1, fnw, h_b);
  transpose_k<<<dim3(256, 64), 256, 0, stream>>>(wg, wbuf, 2048, 8192);
  gemm_k<0><<<dim3(64, 32), 256, 0, stream>>>(h_b, wbuf, bg, nullptr, nullptr,
                                              (void*)g_b, 4096, 8192, 2048);
  transpose_k<<<dim3(256, 64), 256, 0, stream>>>(wva, wbuf, 2048, 8192);
  gemm_k<2><<<dim3(64, 32), 256, 0, stream>>>(h_b, wbuf, bva, nullptr, g_b,
                                              (void*)g_b, 4096, 8192, 2048);
  transpose_k<<<dim3(64, 256), 256, 0, stream>>>(wp, wbuf, 8192, 2048);
  gemm_k<1><<<dim3(16, 32), 256, 0, stream>>>(g_b, wbuf, bp, x1, nullptr,
                                              (void*)out_x, 4096, 2048, 8192);
}

// Round 4
// 1254.306 us; speedup vs baseline: 1.1726x; 1.1038x over previous
//
#include <hip/hip_runtime.h>
#include <stdint.h>

// ---------- types / helpers ----------
typedef __bf16 bf16x8 __attribute__((ext_vector_type(8)));
typedef float  f32x4  __attribute__((ext_vector_type(4)));

__device__ __forceinline__ uint16_t f2b(float f) {
  uint32_t u = __float_as_uint(f);
  u += 0x7fffu + ((u >> 16) & 1u);        // round-to-nearest-even
  return (uint16_t)(u >> 16);
}
__device__ __forceinline__ float b2f(uint16_t h) {
  return __uint_as_float(((uint32_t)h) << 16);
}

// async global->LDS, 16B per lane; LDS dst = wave-uniform base + lane*16
__device__ __forceinline__ void gl_lds16(const uint16_t* g, uint16_t* l) {
  __builtin_amdgcn_global_load_lds(
      (const __attribute__((address_space(1))) uint32_t*)g,
      (__attribute__((address_space(3))) uint32_t*)l, 16, 0, 0);
}

#define MFMA16(a,b,c) __builtin_amdgcn_mfma_f32_16x16x32_bf16((a),(b),(c),0,0,0)

// B=2 S=2048 DIM=2048 HEADS=16 HD=128 FF=8192 PREV=1024 T=3072

// ---------- rmsnorm (f32 in -> bf16 out), row length 2048 ----------
__global__ __launch_bounds__(256)
void rmsnorm_k(const float* __restrict__ x, const float* __restrict__ w,
               uint16_t* __restrict__ out) {
  __shared__ float red[4];
  const int row = blockIdx.x, tid = threadIdx.x;
  const float* xr = x + (size_t)row * 2048;
  const int c = tid * 8;
  float4 a = *(const float4*)&xr[c];
  float4 b = *(const float4*)&xr[c + 4];
  float ss = a.x*a.x + a.y*a.y + a.z*a.z + a.w*a.w
           + b.x*b.x + b.y*b.y + b.z*b.z + b.w*b.w;
  ss += __shfl_xor(ss, 1);  ss += __shfl_xor(ss, 2);  ss += __shfl_xor(ss, 4);
  ss += __shfl_xor(ss, 8);  ss += __shfl_xor(ss, 16); ss += __shfl_xor(ss, 32);
  if ((tid & 63) == 0) red[tid >> 6] = ss;
  __syncthreads();
  const float tot = red[0] + red[1] + red[2] + red[3];
  const float rms = rsqrtf(tot * (1.0f / 2048.0f) + 1e-6f);
  float4 w0 = *(const float4*)&w[c];
  float4 w1 = *(const float4*)&w[c + 4];
  uint16_t* orow = out + (size_t)row * 2048;
  orow[c+0] = f2b(a.x * rms * w0.x); orow[c+1] = f2b(a.y * rms * w0.y);
  orow[c+2] = f2b(a.z * rms * w0.z); orow[c+3] = f2b(a.w * rms * w0.w);
  orow[c+4] = f2b(b.x * rms * w1.x); orow[c+5] = f2b(b.y * rms * w1.y);
  orow[c+6] = f2b(b.z * rms * w1.z); orow[c+7] = f2b(b.w * rms * w1.w);
}

// ---------- bias concat: [bq|bk|bv] -> 6144 f32 ----------
__global__ void biascat_k(const float* __restrict__ bq, const float* __restrict__ bk,
                          const float* __restrict__ bv, float* __restrict__ out) {
  int i = blockIdx.x * 256 + threadIdx.x;
  if (i < 6144)
    out[i] = (i < 2048) ? bq[i] : ((i < 4096) ? bk[i - 2048] : bv[i - 4096]);
}

// ---------- transpose-convert: src (K,N) f32 -> dst (N,K) bf16 ----------
__global__ __launch_bounds__(256)
void transpose_k(const float* __restrict__ src, uint16_t* __restrict__ dst,
                 int K, int N) {
  __shared__ float tile[32][33];
  const int tx = threadIdx.x & 31, ty = threadIdx.x >> 5;   // 32 x 8
  const int n0 = blockIdx.x * 32, k0 = blockIdx.y * 32;
  #pragma unroll
  for (int i = 0; i < 4; ++i)
    tile[ty + i*8][tx] = src[(size_t)(k0 + ty + i*8) * N + n0 + tx];
  __syncthreads();
  #pragma unroll
  for (int i = 0; i < 4; ++i)
    dst[(size_t)(n0 + ty + i*8) * K + k0 + tx] = f2b(tile[tx][ty + i*8]);
}

// ---------- batched V transpose: (32,3072,128) f32 -> (32,128,3072) bf16 ----------
__global__ __launch_bounds__(256)
void transpose_v_k(const float* __restrict__ src, uint16_t* __restrict__ dst) {
  __shared__ float tile[32][33];
  const int tx = threadIdx.x & 31, ty = threadIdx.x >> 5;
  const int t0 = blockIdx.x * 32, d0 = blockIdx.y * 32, bh = blockIdx.z;
  const float* s = src + (size_t)bh * 393216;
  uint16_t*   d = dst + (size_t)bh * 393216;
  #pragma unroll
  for (int i = 0; i < 4; ++i)
    tile[ty + i*8][tx] = s[(size_t)(t0 + ty + i*8) * 128 + d0 + tx];
  __syncthreads();
  #pragma unroll
  for (int i = 0; i < 4; ++i)
    d[(size_t)(d0 + ty + i*8) * 3072 + t0 + tx] = f2b(tile[tx][ty + i*8]);
}

// ---------- KV-cache copy: (BH,1024,128) f32 -> (BH,3072,128) f32 [:1024] ----------
__global__ __launch_bounds__(256)
void copy_cache_k(const float4* __restrict__ src, float4* __restrict__ dst) {
  const int idx = blockIdx.x * 256 + threadIdx.x;      // 1,048,576 total
  const int c4 = idx & 31, t = (idx >> 5) & 1023, bh = idx >> 15;
  dst[((size_t)bh * 3072 + t) * 32 + c4] = src[idx];
}

// ---------- KV-cache copy + fused bf16 convert (K path) ----------
__global__ __launch_bounds__(256)
void copy_cache_kb_k(const float4* __restrict__ src, float4* __restrict__ dst,
                     uint16_t* __restrict__ dstb) {
  const int idx = blockIdx.x * 256 + threadIdx.x;      // 1,048,576 total
  const int c4 = idx & 31, t = (idx >> 5) & 1023, bh = idx >> 15;
  float4 v = src[idx];
  const size_t o = ((size_t)bh * 3072 + t) * 32 + c4;
  dst[o] = v;
  ushort4 b;
  b.x = f2b(v.x); b.y = f2b(v.y); b.z = f2b(v.z); b.w = f2b(v.w);
  ((ushort4*)dstb)[o] = b;
}

// ---------- RoPE + scatter (K also emitted as bf16 -> kbb) ----------
__global__ __launch_bounds__(256)
void rope_k(const uint16_t* __restrict__ qkv, const float* __restrict__ fc,
            const float* __restrict__ fs, uint16_t* __restrict__ qb,
            float* __restrict__ kat, float* __restrict__ vat,
            uint16_t* __restrict__ kbb) {
  const int bi = blockIdx.x;                // B*S*4 = 16384 blocks
  const int bs = bi >> 2;                   // b*2048 + s
  const int h  = ((bi & 3) << 2) + (threadIdx.x >> 6);
  const int d  = threadIdx.x & 63;
  const int b  = bs >> 11, s = bs & 2047;
  const int pos = s + 1024;
  const float c  = fc[pos * 64 + d];
  const float sn = fs[pos * 64 + d];
  const uint16_t* row = qkv + (size_t)bs * 6144 + h * 128;
  const float q0 = b2f(row[2*d]),        q1 = b2f(row[2*d + 1]);
  const float k0 = b2f(row[2048 + 2*d]), k1 = b2f(row[2048 + 2*d + 1]);
  const float v0 = b2f(row[4096 + 2*d]), v1 = b2f(row[4096 + 2*d + 1]);
  const size_t qo = (((size_t)b*16 + h) * 2048 + s) * 128 + 2*d;
  qb[qo]     = f2b(q0 * c - q1 * sn);
  qb[qo + 1] = f2b(q0 * sn + q1 * c);
  const size_t ko = (((size_t)b*16 + h) * 3072 + 1024 + s) * 128 + 2*d;
  const float kr0 = k0 * c - k1 * sn;
  const float kr1 = k0 * sn + k1 * c;
  kat[ko]     = kr0;
  kat[ko + 1] = kr1;
  kbb[ko]     = f2b(kr0);
  kbb[ko + 1] = f2b(kr1);
  vat[ko]     = v0;
  vat[ko + 1] = v1;
}

// ---------- flash attention v3: KVBLK=64, swizzled K+V, deferred l-reduce ----------
__global__ __launch_bounds__(256)
void attn_k(const uint16_t* __restrict__ qb, const uint16_t* __restrict__ kb,
            const uint16_t* __restrict__ vt, uint16_t* __restrict__ ob) {
  __shared__ __align__(16) uint16_t lsK[64 * 128];  // [key][chunk^(key&15)] swizzled
  __shared__ __align__(16) uint16_t lsV[128 * 64];  // [d][chunk^(d&7)] swizzled, ld=64
  __shared__ __align__(16) uint16_t lsP[4][16 * 72];
  const int tid = threadIdx.x;
  const int lane = tid & 63, w = tid >> 6;
  const int l15 = lane & 15, q4 = lane >> 4;
  const int bh = blockIdx.x & 31;                   // b*16+h
  const int qi = 31 - (blockIdx.x >> 5);            // largest-work blocks first
  const int q0 = qi * 64;
  const int s_w = q0 + w * 16;

  int koff[4], voff[4];
  #pragma unroll
  for (int p = 0; p < 4; ++p) {
    const int idk = p * 256 + tid;                  // 1024 chunks of 8 elements
    const int krow = idk >> 4, kch = idk & 15;
    koff[p] = krow * 128 + ((kch ^ (krow & 15)) << 3);
    const int dd = idk >> 3, vch = idk & 7;
    voff[p] = dd * 3072 + ((vch ^ (dd & 7)) << 3);
  }
  const uint16_t* kbh = kb + (size_t)bh * 3072 * 128;
  const uint16_t* vbh = vt + (size_t)bh * 128 * 3072;

  bf16x8 qf[4];
  const uint16_t* qrow = qb + ((size_t)bh * 2048 + s_w + l15) * 128;
  #pragma unroll
  for (int kc = 0; kc < 4; ++kc)
    qf[kc] = *(const bf16x8*)&qrow[kc * 32 + q4 * 8];

  f32x4 o[8];
  #pragma unroll
  for (int nt = 0; nt < 8; ++nt) o[nt] = (f32x4){0.f, 0.f, 0.f, 0.f};
  float mrow[4], lrow[4];
  #pragma unroll
  for (int r = 0; r < 4; ++r) { mrow[r] = -1e38f; lrow[r] = 0.f; }

  const float SC = 0.08838834764831845f * 1.4426950408889634f;
  const int ntiles = qi + 17;                       // 64-key tiles
  const int limw = 1024 + s_w + 15;                 // wave's largest allowed key

  for (int tt = 0; tt < ntiles; ++tt) {
    const int t0 = tt << 6;
    __syncthreads();
    #pragma unroll
    for (int p = 0; p < 4; ++p) {
      gl_lds16(kbh + (size_t)t0 * 128 + koff[p], &lsK[(p * 256 + w * 64) * 8]);
      gl_lds16(vbh + t0 + voff[p],               &lsV[(p * 256 + w * 64) * 8]);
    }
    __syncthreads();
    if (t0 > limw) continue;                        // fully masked for this wave

    f32x4 s[4];
    #pragma unroll
    for (int kg = 0; kg < 4; ++kg) s[kg] = (f32x4){0.f,0.f,0.f,0.f};
    #pragma unroll
    for (int kc = 0; kc < 4; ++kc) {
      const int chp = ((kc * 4 + q4) ^ l15) << 3;
      bf16x8 kf0 = *(const bf16x8*)&lsK[ l15       * 128 + chp];
      bf16x8 kf1 = *(const bf16x8*)&lsK[(16 + l15) * 128 + chp];
      bf16x8 kf2 = *(const bf16x8*)&lsK[(32 + l15) * 128 + chp];
      bf16x8 kf3 = *(const bf16x8*)&lsK[(48 + l15) * 128 + chp];
      s[0] = MFMA16(qf[kc], kf0, s[0]);
      s[1] = MFMA16(qf[kc], kf1, s[1]);
      s[2] = MFMA16(qf[kc], kf2, s[2]);
      s[3] = MFMA16(qf[kc], kf3, s[3]);
    }
    if (t0 + 63 > 1024 + s_w) {                     // diagonal tile: mask
      #pragma unroll
      for (int r = 0; r < 4; ++r) {
        const int lim = 1024 + s_w + q4 * 4 + r;
        if (t0 +      l15 > lim) s[0][r] = -1e38f;
        if (t0 + 16 + l15 > lim) s[1][r] = -1e38f;
        if (t0 + 32 + l15 > lim) s[2][r] = -1e38f;
        if (t0 + 48 + l15 > lim) s[3][r] = -1e38f;
      }
    }
    float alpha[4];
    #pragma unroll
    for (int r = 0; r < 4; ++r) {
      float v = fmaxf(fmaxf(s[0][r], s[1][r]), fmaxf(s[2][r], s[3][r]));
      v = fmaxf(v, __shfl_xor(v, 1)); v = fmaxf(v, __shfl_xor(v, 2));
      v = fmaxf(v, __shfl_xor(v, 4)); v = fmaxf(v, __shfl_xor(v, 8));
      const float mn = fmaxf(mrow[r], v);
      alpha[r] = exp2f((mrow[r] - mn) * SC);
      mrow[r] = mn;
    }
    #pragma unroll
    for (int r = 0; r < 4; ++r) {
      const float nm = -mrow[r] * SC;
      const float p0 = exp2f(fmaf(s[0][r], SC, nm));
      const float p1 = exp2f(fmaf(s[1][r], SC, nm));
      const float p2 = exp2f(fmaf(s[2][r], SC, nm));
      const float p3 = exp2f(fmaf(s[3][r], SC, nm));
      lrow[r] = fmaf(lrow[r], alpha[r], (p0 + p1) + (p2 + p3));
      const int pr = (q4 * 4 + r) * 72;
      lsP[w][pr +      l15] = f2b(p0);
      lsP[w][pr + 16 + l15] = f2b(p1);
      lsP[w][pr + 32 + l15] = f2b(p2);
      lsP[w][pr + 48 + l15] = f2b(p3);
    }
    const float as = alpha[0] * alpha[1] * alpha[2] * alpha[3];
    if (__any(as != 1.0f)) {
      #pragma unroll
      for (int nt = 0; nt < 8; ++nt)
        #pragma unroll
        for (int r = 0; r < 4; ++r) o[nt][r] *= alpha[r];
    }
    bf16x8 pf0 = *(const bf16x8*)&lsP[w][l15 * 72      + q4 * 8];
    bf16x8 pf1 = *(const bf16x8*)&lsP[w][l15 * 72 + 32 + q4 * 8];
    #pragma unroll
    for (int nt = 0; nt < 8; ++nt) {
      const int d = nt * 16 + l15;
      bf16x8 vf0 = *(const bf16x8*)&lsV[d * 64 + (( q4      ^ (d & 7)) << 3)];
      bf16x8 vf1 = *(const bf16x8*)&lsV[d * 64 + (((4 + q4) ^ (d & 7)) << 3)];
      o[nt] = MFMA16(pf0, vf0, o[nt]);
      o[nt] = MFMA16(pf1, vf1, o[nt]);
    }
  }
  const int b = bh >> 4, h = bh & 15;
  #pragma unroll
  for (int r = 0; r < 4; ++r) {
    float l = lrow[r];
    l += __shfl_xor(l, 1); l += __shfl_xor(l, 2);
    l += __shfl_xor(l, 4); l += __shfl_xor(l, 8);
    const float inv = 1.0f / l;
    const int s = s_w + q4 * 4 + r;
    uint16_t* orow = ob + ((size_t)b * 2048 + s) * 2048 + h * 128;
    #pragma unroll
    for (int nt = 0; nt < 8; ++nt)
      orow[nt * 16 + l15] = f2b(o[nt][r] * inv);
  }
}

// ---------- GEMM v2: BN=256 tile, BK=64, 512 thr, dbuf + counted-vmcnt pipeline ----------
// MR = m-fragments per wave (4 or 8) -> BM = MR*32.  8 waves as 2(M) x 4(N).
// LDS: lsA[2buf][2kk][BM][32] + lsB[2buf][2kk][256][32], chunk-swizzled
// (natural chunk c of row stored at slot c ^ ((row>>1)&3); same XOR on read).
// Pipeline invariant at each barrier: next-needed kk-half fully landed (own
// vmcnt before barrier + barrier = cross-wave visibility); AL+2 loads stay
// in flight across barriers (never vmcnt(0) until the peeled last tile).
template <int MR, int EPI>
__global__ __launch_bounds__(512, 2)
void gemm256_k(const uint16_t* __restrict__ A, const uint16_t* __restrict__ Bt,
               const float* __restrict__ bias, const float* __restrict__ resid,
               const uint16_t* __restrict__ gbuf, void* __restrict__ outp,
               int M, int N, int K) {
  constexpr int BM = MR * 32;
  constexpr int AL = BM / 128;               // A stage loads per wave per kk-half
  extern __shared__ __align__(16) uint16_t dynls[];
  uint16_t* lsA = dynls;                     // [2][2][BM][32]
  uint16_t* lsB = dynls + 4 * BM * 32;       // [2][2][256][32]

  const int tid = threadIdx.x;
  const int lane = tid & 63, w = tid >> 6;   // 8 waves
  const int l15 = lane & 15, q4 = lane >> 4;
  const int wm = w & 1, wn = w >> 1;         // 2 x 4

  // bijective XCD-aware block swizzle
  const int nwg = gridDim.x * gridDim.y;
  const int orig = blockIdx.y * gridDim.x + blockIdx.x;
  const int qq = nwg >> 3, rr = nwg & 7;
  const int xcd = orig & 7, loc = orig >> 3;
  const int wgid = (xcd < rr ? xcd * (qq + 1) : rr * (qq + 1) + (xcd - rr) * qq) + loc;
  const int n0 = (wgid % gridDim.x) * 256;
  const int m0 = (wgid / gridDim.x) * BM;

  // staging source coords: chunk g -> LDS slot (row=g>>2, s=g&3) holds natural
  // chunk s ^ ((row>>1)&3), so source chunk = (g&3) ^ ((g>>3)&3).
  int arow[AL], acsl[AL];
  #pragma unroll
  for (int j = 0; j < AL; ++j) {
    const int g = (w * AL + j) * 64 + lane;
    arow[j] = g >> 2;
    acsl[j] = (((g & 3) ^ ((g >> 3) & 3)) << 3);
  }
  int brow[2], bcsl[2];
  #pragma unroll
  for (int j = 0; j < 2; ++j) {
    const int g = (w * 2 + j) * 64 + lane;
    brow[j] = g >> 2;
    bcsl[j] = (((g & 3) ^ ((g >> 3) & 3)) << 3);
  }
  const uint16_t* Ab = A + (size_t)m0 * K;
  const uint16_t* Bb = Bt + (size_t)n0 * K;

  f32x4 acc[MR][4];
  #pragma unroll
  for (int m = 0; m < MR; ++m)
    #pragma unroll
    for (int n = 0; n < 4; ++n) acc[m][n] = (f32x4){0.f, 0.f, 0.f, 0.f};

  auto STAGE = [&](int kt, int b, int kk) {
    const int kbase = kt * 64 + kk * 32;
    #pragma unroll
    for (int j = 0; j < AL; ++j)
      gl_lds16(Ab + (size_t)arow[j] * K + kbase + acsl[j],
               lsA + (b * 2 + kk) * (BM * 32) + (w * AL + j) * 512);
    #pragma unroll
    for (int j = 0; j < 2; ++j)
      gl_lds16(Bb + (size_t)brow[j] * K + kbase + bcsl[j],
               lsB + (b * 2 + kk) * 8192 + (w * 2 + j) * 512);
  };
  auto COMPUTE = [&](int b, int kk) {
    bf16x8 af[MR], bfr[4];
    #pragma unroll
    for (int m = 0; m < MR; ++m) {
      const int row = wm * (BM / 2) + m * 16 + l15;
      af[m] = *(const bf16x8*)(lsA + ((b * 2 + kk) * BM + row) * 32 +
                               ((q4 ^ ((row >> 1) & 3)) << 3));
    }
    #pragma unroll
    for (int n = 0; n < 4; ++n) {
      const int row = wn * 64 + n * 16 + l15;
      bfr[n] = *(const bf16x8*)(lsB + (b * 2 + kk) * 8192 + row * 32 +
                                ((q4 ^ ((row >> 1) & 3)) << 3));
    }
    __builtin_amdgcn_s_setprio(1);
    #pragma unroll
    for (int m = 0; m < MR; ++m)
      #pragma unroll
      for (int n = 0; n < 4; ++n)
        acc[m][n] = MFMA16(af[m], bfr[n], acc[m][n]);
    __builtin_amdgcn_s_setprio(0);
  };
  auto WAITP = [&](bool pf) {
    if (pf) {
      if constexpr (AL == 2) asm volatile("s_waitcnt vmcnt(4)" ::: "memory");
      else                   asm volatile("s_waitcnt vmcnt(3)" ::: "memory");
    } else {
      asm volatile("s_waitcnt vmcnt(0)" ::: "memory");
    }
  };

  const int nK = K >> 6;
  STAGE(0, 0, 0);
  STAGE(0, 0, 1);
  WAITP(true);                               // tile0 kk0 landed; kk1 in flight
  __builtin_amdgcn_s_barrier();
  asm volatile("" ::: "memory");

  for (int t = 0; t < nK; ++t) {
    const int b = t & 1;
    const bool pf = (t + 1 < nK);
    if (pf) STAGE(t + 1, b ^ 1, 0);          // issue early: hides under compute
    COMPUTE(b, 0);
    WAITP(pf);                               // t's kk1 landed (t+1 kk0 in flight)
    __builtin_amdgcn_s_barrier();
    asm volatile("" ::: "memory");
    if (pf) STAGE(t + 1, b ^ 1, 1);
    COMPUTE(b, 1);
    WAITP(pf);                               // t+1's kk0 landed (kk1 in flight)
    __builtin_amdgcn_s_barrier();
    asm volatile("" ::: "memory");
  }

  #pragma unroll
  for (int m = 0; m < MR; ++m) {
    #pragma unroll
    for (int n = 0; n < 4; ++n) {
      const int nn = n0 + wn * 64 + n * 16 + l15;
      const float bn = bias[nn];
      #pragma unroll
      for (int r = 0; r < 4; ++r) {
        const int mm = m0 + wm * (BM / 2) + m * 16 + q4 * 4 + r;
        const size_t off = (size_t)mm * N + nn;
        const float v = acc[m][n][r] + bn;
        if (EPI == 0) {
          ((uint16_t*)outp)[off] = f2b(v);
        } else if (EPI == 1) {
          ((float*)outp)[off] = v + resid[off];
        } else {
          const float g = b2f(gbuf[off]);
          const float sg = g / (1.0f + __expf(-g));
          ((uint16_t*)outp)[off] = f2b(sg * v);
        }
      }
    }
  }
}

// ---------- launch ----------
extern "C" void kernel_launch(void* const* d_in, const int* in_sizes, int n_in,
                              void* d_out, int out_size, void* d_ws, size_t ws_size,
                              hipStream_t stream) {
  const float* x   = (const float*)d_in[0];
  const float* kc  = (const float*)d_in[1];
  const float* vc  = (const float*)d_in[2];
  const float* anw = (const float*)d_in[3];
  const float* fnw = (const float*)d_in[4];
  const float* wq  = (const float*)d_in[5];
  const float* bq  = (const float*)d_in[6];
  const float* wk  = (const float*)d_in[7];
  const float* bk  = (const float*)d_in[8];
  const float* wv_ = (const float*)d_in[9];
  const float* bv  = (const float*)d_in[10];
  const float* wo  = (const float*)d_in[11];
  const float* bo  = (const float*)d_in[12];
  const float* wg  = (const float*)d_in[13];
  const float* bg  = (const float*)d_in[14];
  const float* wva = (const float*)d_in[15];
  const float* bva = (const float*)d_in[16];
  const float* wp  = (const float*)d_in[17];
  const float* bp  = (const float*)d_in[18];
  const float* fc  = (const float*)d_in[19];
  const float* fs  = (const float*)d_in[20];

  float* out_x = (float*)d_out;               // (2,2048,2048)
  float* kat = out_x + 8388608;               // (2,16,3072,128)
  float* vat = kat + 12582912;

  char* ws = (char*)d_ws;
  uint16_t* h_b   = (uint16_t*)(ws);                       // [0,16M)   h bf16
  uint16_t* wbuf  = (uint16_t*)(ws + 16777216);            // [16M,48M) transposed weights
  uint16_t* k_b   = (uint16_t*)(ws);                       // [0,24M)   K bf16 (attn window)
  uint16_t* v_t   = (uint16_t*)(ws + 25165824);            // [24M,48M) V bf16 T (attn window)
  uint16_t* qkv_b = (uint16_t*)(ws + 50331648);            // [48M,96M) qkv bf16
  uint16_t* q_b   = (uint16_t*)(ws + 100663296);           // [96M,112M) roped Q
  uint16_t* o_b   = (uint16_t*)(ws + 117440512);           // [112M,128M) attn out
  float*    x1    = (float*)   (ws + 134217728);           // [128M,160M) post-attn residual
  float*    bcat  = (float*)   (ws + 167772160);           // 24 KB
  uint16_t* g_b   = qkv_b;                                 // FFN overlay [48M,112M)

  // dynamic-LDS opt-in (>64KB): MR=4 -> 96KB, MR=8 -> 128KB
  {
    auto f40 = gemm256_k<4, 0>; auto f41 = gemm256_k<4, 1>;
    auto f80 = gemm256_k<8, 0>; auto f82 = gemm256_k<8, 2>;
    (void)hipFuncSetAttribute((const void*)f40,
        hipFuncAttributeMaxDynamicSharedMemorySize, 98304);
    (void)hipFuncSetAttribute((const void*)f41,
        hipFuncAttributeMaxDynamicSharedMemorySize, 98304);
    (void)hipFuncSetAttribute((const void*)f80,
        hipFuncAttributeMaxDynamicSharedMemorySize, 131072);
    (void)hipFuncSetAttribute((const void*)f82,
        hipFuncAttributeMaxDynamicSharedMemorySize, 131072);
  }

  // attention block
  rmsnorm_k<<<4096, 256, 0, stream>>>(x, anw, h_b);
  biascat_k<<<24, 256, 0, stream>>>(bq, bk, bv, bcat);
  transpose_k<<<dim3(64, 64), 256, 0, stream>>>(wq,  wbuf,               2048, 2048);
  transpose_k<<<dim3(64, 64), 256, 0, stream>>>(wk,  wbuf + 1*2048*2048, 2048, 2048);
  transpose_k<<<dim3(64, 64), 256, 0, stream>>>(wv_, wbuf + 2*2048*2048, 2048, 2048);
  gemm256_k<4,0><<<dim3(24, 32), 512, 98304, stream>>>(h_b, wbuf, bcat, nullptr,
                                              nullptr, (void*)qkv_b, 4096, 6144, 2048);
  copy_cache_kb_k<<<4096, 256, 0, stream>>>((const float4*)kc, (float4*)kat, k_b);
  copy_cache_k<<<4096, 256, 0, stream>>>((const float4*)vc, (float4*)vat);
  rope_k<<<16384, 256, 0, stream>>>(qkv_b, fc, fs, q_b, kat, vat, k_b);
  transpose_v_k<<<dim3(96, 4, 32), 256, 0, stream>>>(vat, v_t);   // V -> bf16 [d][t]
  attn_k<<<1024, 256, 0, stream>>>(q_b, k_b, v_t, o_b);
  transpose_k<<<dim3(64, 64), 256, 0, stream>>>(wo, wbuf, 2048, 2048);
  gemm256_k<4,1><<<dim3(8, 32), 512, 98304, stream>>>(o_b, wbuf, bo, x, nullptr,
                                              (void*)x1, 4096, 2048, 2048);
  // FFN block
  rmsnorm_k<<<4096, 256, 0, stream>>>(x1, fnw, h_b);
  transpose_k<<<dim3(256, 64), 256, 0, stream>>>(wg, wbuf, 2048, 8192);
  gemm256_k<8,0><<<dim3(32, 16), 512, 131072, stream>>>(h_b, wbuf, bg, nullptr,
                                              nullptr, (void*)g_b, 4096, 8192, 2048);
  transpose_k<<<dim3(256, 64), 256, 0, stream>>>(wva, wbuf, 2048, 8192);
  gemm256_k<8,2><<<dim3(32, 16), 512, 131072, stream>>>(h_b, wbuf, bva, nullptr,
                                              g_b, (void*)g_b, 4096, 8192, 2048);
  transpose_k<<<dim3(64, 256), 256, 0, stream>>>(wp, wbuf, 8192, 2048);
  gemm256_k<4,1><<<dim3(8, 32), 512, 98304, stream>>>(g_b, wbuf, bp, x1, nullptr,
                                              (void*)out_x, 4096, 2048, 8192);
}